// Round 4
// baseline (6234.251 us; speedup 1.0000x reference)
//
#include <hip/hip_runtime.h>
#include <stdint.h>

#define NNODES 2048
#define T_SEQ  2048
#define HD     640
#define GD     2560   // 4*HD
#define KIN    8500
#define NEDGE  65536
#define NGRAPH 16

// fused_scan geometry: 3 layers x 80 blocks x 8 dims, 512 threads (8 waves).
// Record row: 80 records x 3 u64 (3 f16 h + 16-bit seq each) = 240 u64.
#define LSB    80     // blocks per layer
#define LDIM   8      // h-dims per block
#define ROW64  240    // u64 per timestep row
#define RECL   (T_SEQ * ROW64)   // u64 per layer record buffer

typedef unsigned long long u64;
typedef _Float16 half2v __attribute__((ext_vector_type(2)));
using short8 = __attribute__((ext_vector_type(8))) short;
using f32x4  = __attribute__((ext_vector_type(4))) float;

#if __has_builtin(__builtin_amdgcn_fdot2)
#define HAVE_FDOT2 1
#endif

__device__ __forceinline__ float dot2acc(unsigned w, unsigned h, float acc) {
#ifdef HAVE_FDOT2
  return __builtin_amdgcn_fdot2(__builtin_bit_cast(half2v, w),
                                __builtin_bit_cast(half2v, h), acc, false);
#else
  acc += (float)__builtin_bit_cast(_Float16, (unsigned short)(w & 0xffffu)) *
         (float)__builtin_bit_cast(_Float16, (unsigned short)(h & 0xffffu));
  acc += (float)__builtin_bit_cast(_Float16, (unsigned short)(w >> 16)) *
         (float)__builtin_bit_cast(_Float16, (unsigned short)(h >> 16));
  return acc;
#endif
}

__device__ __forceinline__ unsigned short f2h(float x) {
  return __builtin_bit_cast(unsigned short, (_Float16)x);
}
__device__ __forceinline__ unsigned packh(float a, float b) {
  return (unsigned)f2h(a) | ((unsigned)f2h(b) << 16);
}
__device__ __forceinline__ unsigned f2bf(float x) {
  unsigned u = __float_as_uint(x);
  return (u + 0x7fffu + ((u >> 16) & 1u)) >> 16;
}
__device__ __forceinline__ unsigned packbf(float a, float b) {
  return f2bf(a) | (f2bf(b) << 16);
}

// ---------------------------------------------------------------------------
// C[M,N] = A[M,K] @ W[N,K]^T + b1[n] + b2[n], bf16 MFMA 16x16x32. (unchanged)
// ---------------------------------------------------------------------------
#define GK 32
__global__ __launch_bounds__(256) void gemm_mfma(
    const float* __restrict__ A, const float* __restrict__ W,
    const float* __restrict__ b1, const float* __restrict__ b2,
    float* __restrict__ C, int M, int N, int K) {
  __shared__ __align__(16) short As[128 * 40];
  __shared__ __align__(16) short Ws[128 * 40];
  const int tid = threadIdx.x;
  const int wave = tid >> 6, lane = tid & 63;
  const int bm = blockIdx.y * 128, bn = blockIdx.x * 128;
  const int wm = (wave >> 1) * 64, wn = (wave & 1) * 64;
  const int mrow = lane & 15, quad = lane >> 4;
  const int srow = tid >> 1, skc = (tid & 1) * 16;
  f32x4 acc[4][4] = {};
  for (int k0 = 0; k0 < K; k0 += GK) {
    float av[16], wv[16];
    if (k0 + GK <= K) {
      const float* Ap = A + (long)(bm + srow) * K + k0 + skc;
      const float* Wp = W + (long)(bn + srow) * K + k0 + skc;
#pragma unroll
      for (int i = 0; i < 4; i++) {
        float4 a4 = *(const float4*)(Ap + 4 * i);
        float4 w4 = *(const float4*)(Wp + 4 * i);
        av[4*i]=a4.x; av[4*i+1]=a4.y; av[4*i+2]=a4.z; av[4*i+3]=a4.w;
        wv[4*i]=w4.x; wv[4*i+1]=w4.y; wv[4*i+2]=w4.z; wv[4*i+3]=w4.w;
      }
    } else {
#pragma unroll
      for (int i = 0; i < 16; i++) {
        const int k = k0 + skc + i;
        av[i] = (k < K) ? A[(long)(bm + srow) * K + k] : 0.f;
        wv[i] = (k < K) ? W[(long)(bn + srow) * K + k] : 0.f;
      }
    }
    __syncthreads();
    {
      uint4* pa = (uint4*)&As[srow * 40 + skc];
      uint4* pw = (uint4*)&Ws[srow * 40 + skc];
      pa[0] = make_uint4(packbf(av[0],av[1]), packbf(av[2],av[3]),
                         packbf(av[4],av[5]), packbf(av[6],av[7]));
      pa[1] = make_uint4(packbf(av[8],av[9]), packbf(av[10],av[11]),
                         packbf(av[12],av[13]), packbf(av[14],av[15]));
      pw[0] = make_uint4(packbf(wv[0],wv[1]), packbf(wv[2],wv[3]),
                         packbf(wv[4],wv[5]), packbf(wv[6],wv[7]));
      pw[1] = make_uint4(packbf(wv[8],wv[9]), packbf(wv[10],wv[11]),
                         packbf(wv[12],wv[13]), packbf(wv[14],wv[15]));
    }
    __syncthreads();
    short8 af[4], bf[4];
#pragma unroll
    for (int mi = 0; mi < 4; mi++)
      af[mi] = *(const short8*)&As[(wm + mi * 16 + mrow) * 40 + quad * 8];
#pragma unroll
    for (int ni = 0; ni < 4; ni++)
      bf[ni] = *(const short8*)&Ws[(wn + ni * 16 + mrow) * 40 + quad * 8];
#pragma unroll
    for (int mi = 0; mi < 4; mi++)
#pragma unroll
      for (int ni = 0; ni < 4; ni++)
        acc[mi][ni] = __builtin_amdgcn_mfma_f32_16x16x32_bf16(
            af[mi], bf[ni], acc[mi][ni], 0, 0, 0);
  }
#pragma unroll
  for (int ni = 0; ni < 4; ni++) {
    const int c = bn + wn + ni * 16 + mrow;
    const float bias = b1[c] + b2[c];
#pragma unroll
    for (int mi = 0; mi < 4; mi++) {
      const int r0 = bm + wm + mi * 16 + quad * 4;
#pragma unroll
      for (int reg = 0; reg < 4; reg++)
        C[(long)(r0 + reg) * N + c] = acc[mi][ni][reg] + bias;
    }
  }
}

// ---------------------------------------------------------------------------
// Fused 3-layer pipelined LSTM scan.
// 80 blocks/layer x 8 dims, 512 threads (8 waves). Weights in registers:
// lane (row=l&31, k-half=l>>5) holds 40 f16 hh (+40 f16 ih) = 20(40) u32.
// r3 lesson: without pinning, the allocator REMATERIALIZES these loads into
// the t-loop (VGPR_Count=48, FETCH 225MB, weights re-streamed per step).
// Fix: opaque empty-asm "+v" per packed value after staging — the compiler
// cannot remat an unknown asm's output, so the values stay VGPR-resident.
// Records: 3 u64 per block row (3 f16 h + seq<<48), agent-scope everywhere.
// One __syncthreads per step; pdot parity-double-buffered.
// ---------------------------------------------------------------------------
__global__ __launch_bounds__(512, 2) void fused_scan(
    const float* __restrict__ xp,
    const float* __restrict__ whh0,
    const float* __restrict__ wih1, const float* __restrict__ whh1,
    const float* __restrict__ bih1, const float* __restrict__ bhh1,
    const float* __restrict__ wih2, const float* __restrict__ whh2,
    const float* __restrict__ bih2, const float* __restrict__ bhh2,
    u64* __restrict__ rec0, u64* __restrict__ rec1, u64* __restrict__ rec2,
    float* __restrict__ hs2) {
  const int l = blockIdx.x / LSB, blk = blockIdx.x % LSB;
  const int tid = threadIdx.x, wv = tid >> 6, lane = tid & 63;

  __shared__ __align__(16) unsigned short hbufh[640];  // own-layer h (t-1)
  __shared__ __align__(16) unsigned short xbufh[640];  // upstream x (t)
  __shared__ float pdot[2][8][32];                     // [parity][wave][row]

  const float* Wih = (l == 1) ? wih1 : wih2;
  const float* Whh = (l == 0) ? whh0 : ((l == 1) ? whh1 : whh2);
  const float* bi  = (l == 1) ? bih1 : bih2;
  const float* bh  = (l == 1) ? bhh1 : bhh2;
  u64* recL = (l == 0) ? rec0 : ((l == 1) ? rec1 : rec2);
  const u64* recU = (l == 1) ? rec0 : rec1;

  // ---- stage weights into registers (small per-lane slice, one-time)
  const int r = lane & 31, kh = lane >> 5;     // row 0..31, k-half 0..1
  const int gq = r >> 3, dd = r & 7;           // gate, dim
  const long wro = (long)(gq * HD + blk * LDIM + dd) * HD + 80 * wv + 40 * kh;
  unsigned wh[20], wx[20];
#pragma unroll
  for (int i = 0; i < 10; ++i) {
    float4 a = *(const float4*)(Whh + wro + 4 * i);
    wh[2 * i]     = packh(a.x, a.y);
    wh[2 * i + 1] = packh(a.z, a.w);
  }
  if (l > 0) {
#pragma unroll
    for (int i = 0; i < 10; ++i) {
      float4 a = *(const float4*)(Wih + wro + 4 * i);
      wx[2 * i]     = packh(a.x, a.y);
      wx[2 * i + 1] = packh(a.z, a.w);
    }
  }
  // ---- PIN: make packed weights opaque so the allocator can neither
  // rematerialize the loads (r3: VGPR=48, 225MB refetch) nor fold them.
#pragma unroll
  for (int i = 0; i < 20; ++i) asm volatile("" : "+v"(wh[i]));
  if (l > 0) {
#pragma unroll
    for (int i = 0; i < 20; ++i) asm volatile("" : "+v"(wx[i]));
  }

  // ---- gate-row external term (wave 0, lanes<32): xp row (l==0) or bias sum
  const int gidx = (lane >> 3) * HD + blk * LDIM + (lane & 7);
  float extb = 0.f, creg = 0.f;
  if (wv == 0 && lane < 32)
    extb = (l == 0) ? xp[gidx] : (bi[gidx] + bh[gidx]);

  // ---- zero own h slice (wave-private: dims [80*wv, 80*wv+80))
  unsigned* hbuf32 = (unsigned*)hbufh;
  unsigned* xbuf32 = (unsigned*)xbufh;
  if (lane < 40) { hbuf32[40 * wv + lane] = 0; xbuf32[40 * wv + lane] = 0; }
  __syncthreads();

  // ---- poll geometry: wave covers records [10*wv, 10*wv+10), 3 u64 each.
  // lanes 0..29 poll own layer (t-1); lanes 32..61 poll upstream (t), l>0.
  const bool isA = (lane < 30);
  const bool isB = (l > 0) && (lane >= 32) && (lane < 62);
  const int p = isA ? lane : (lane - 32);
  const int dimb = 80 * wv + (p / 3) * LDIM + 3 * (p % 3);
  const int ncnt = ((p % 3) == 2) ? 2 : 3;
  unsigned short* slot = (isA ? hbufh : xbufh) + dimb;

  long totspins = 0;
  for (int t = 0; t < T_SEQ; ++t) {
    // ---- poll + unpack
    const bool want = (isA && t > 0) || isB;
    if (want && totspins < 30000000L) {
      const u64* src = isA ? (recL + (long)(t - 1) * ROW64 + 30 * wv + p)
                           : (recU + (long)t * ROW64 + 30 * wv + p);
      const unsigned exps = isA ? (unsigned)t : (unsigned)(t + 1);
      int ss = 0;
      for (;;) {
        const u64 v = __hip_atomic_load(src, __ATOMIC_RELAXED,
                                        __HIP_MEMORY_SCOPE_AGENT);
        if ((unsigned)(v >> 48) == exps) {
          slot[0] = (unsigned short)v;
          slot[1] = (unsigned short)(v >> 16);
          if (ncnt == 3) slot[2] = (unsigned short)(v >> 32);
          break;
        }
        ++totspins;
        if (++ss > 2) __builtin_amdgcn_s_sleep(1);
        if (totspins > 30000000L) break;   // safety: wrong > hung
      }
    }
    __threadfence_block();   // order LDS unpack writes before same-wave reads

    // ---- dot: lane row r, k chunk [80*wv + 40*kh, +40); consume uint4
    // immediately (no hc[] temp array -> lower peak VGPR pressure)
    float a = 0.f;
    {
      const uint4* hb = (const uint4*)&hbuf32[40 * wv + 20 * kh];
#pragma unroll
      for (int i = 0; i < 5; ++i) {
        const uint4 q = hb[i];
        a = dot2acc(wh[4 * i + 0], q.x, a);
        a = dot2acc(wh[4 * i + 1], q.y, a);
        a = dot2acc(wh[4 * i + 2], q.z, a);
        a = dot2acc(wh[4 * i + 3], q.w, a);
      }
    }
    if (l > 0) {
      const uint4* xb = (const uint4*)&xbuf32[40 * wv + 20 * kh];
#pragma unroll
      for (int i = 0; i < 5; ++i) {
        const uint4 q = xb[i];
        a = dot2acc(wx[4 * i + 0], q.x, a);
        a = dot2acc(wx[4 * i + 1], q.y, a);
        a = dot2acc(wx[4 * i + 2], q.z, a);
        a = dot2acc(wx[4 * i + 3], q.w, a);
      }
    }
    a += __shfl_xor(a, 32);                 // combine k-halves
    if (lane < 32) pdot[t & 1][wv][lane] = a;
    __syncthreads();   // pdot ready (single barrier per step)

    // ---- gates (wave 0, lanes<32 rows; lanes<8 cell/output)
    if (wv == 0) {
      const int par = t & 1;
      float av = 0.f;
      if (lane < 32) {
        float s = extb;
#pragma unroll
        for (int w = 0; w < 8; ++w) s += pdot[par][w][lane];
        if ((lane >> 3) == 2) {            // g gate: tanh
          const float e2 = __expf(2.f * s);
          av = 1.f - 2.f / (e2 + 1.f);
        } else {                           // i, f, o: sigmoid
          av = 1.f / (1.f + __expf(-s));
        }
      }
      const float ai = av;
      const float af = __shfl(av, lane + 8);
      const float ag = __shfl(av, lane + 16);
      const float ao = __shfl(av, lane + 24);
      float h = 0.f;
      if (lane < LDIM) {
        creg = af * creg + ai * ag;
        const float e2 = __expf(2.f * creg);
        h = ao * (1.f - 2.f / (e2 + 1.f));
        if (l == 2) hs2[(long)t * HD + blk * LDIM + lane] = h;
      }
      // pack 8 h into 3 u64 (3 f16 + seq each) and publish
      const float ha = __shfl(h, 3 * lane);
      const float hb2 = __shfl(h, 3 * lane + 1);
      const float hc2 = __shfl(h, 3 * lane + 2);
      if (lane < 3) {
        const unsigned seq = (unsigned)(t + 1);
        const u64 val = (u64)((unsigned)f2h(ha) | ((unsigned)f2h(hb2) << 16)) |
                        ((u64)((unsigned)f2h(hc2) | (seq << 16)) << 32);
        __hip_atomic_store(recL + (long)t * ROW64 + 3 * blk + lane, val,
                           __ATOMIC_RELAXED, __HIP_MEMORY_SCOPE_AGENT);
      }
      if (l == 0 && lane < 32 && t + 1 < T_SEQ)
        extb = xp[(long)(t + 1) * GD + gidx];   // prefetch next step
    }
  }
}

// ---------------------------------------------------------------------------
// GCN pieces (unchanged)
// ---------------------------------------------------------------------------
__global__ __launch_bounds__(256) void gcn_gemm(
    const float* __restrict__ X, const float* __restrict__ W,
    float* __restrict__ Y, int di, int dout) {
  __shared__ float xr[640];
  const int n = blockIdx.x;
  for (int k = threadIdx.x; k < di; k += 256) xr[k] = X[(long)n * di + k];
  __syncthreads();
  for (int c = threadIdx.x; c < dout; c += 256) {
    float acc = 0.f;
    for (int k = 0; k < di; k++) acc = fmaf(xr[k], W[(long)k * dout + c], acc);
    Y[(long)n * dout + c] = acc;
  }
}

__global__ void deg_kernel(const int* __restrict__ dst, unsigned int* __restrict__ deg) {
  const int e = blockIdx.x * 256 + threadIdx.x;
  if (e < NEDGE) atomicAdd(&deg[dst[e]], 1u);
}

__global__ void dinv_kernel(const unsigned int* __restrict__ deg, float* __restrict__ dinv) {
  const int n = blockIdx.x * 256 + threadIdx.x;
  if (n < NNODES) dinv[n] = 1.f / sqrtf((float)(deg[n] + 1u));
}

__global__ __launch_bounds__(128) void gcn_scatter(
    const float* __restrict__ XW, const int* __restrict__ src,
    const int* __restrict__ dst, const float* __restrict__ dinv,
    float* __restrict__ out, int dout) {
  const int e = blockIdx.x;
  const int s = src[e], d = dst[e];
  const float nrm = dinv[s] * dinv[d];
  for (int c = threadIdx.x; c < dout; c += 128)
    atomicAdd(&out[(long)d * dout + c], XW[(long)s * dout + c] * nrm);
}

__global__ __launch_bounds__(256) void gcn_bn(
    const float* __restrict__ scat, const float* __restrict__ xw,
    const float* __restrict__ dinv, const float* __restrict__ bias,
    float* __restrict__ out, int dout) {
  const int c = blockIdx.x;
  const float bc = bias[c];
  float s = 0.f, s2 = 0.f;
  for (int n = threadIdx.x; n < NNODES; n += 256) {
    float v = scat[(long)n * dout + c] + xw[(long)n * dout + c] * dinv[n] * dinv[n] + bc;
    v = v >= 0.f ? v : 0.01f * v;
    s += v; s2 += v * v;
  }
  __shared__ float rs[4], rs2[4];
#pragma unroll
  for (int off = 32; off; off >>= 1) { s += __shfl_down(s, off, 64); s2 += __shfl_down(s2, off, 64); }
  const int w = threadIdx.x >> 6;
  if ((threadIdx.x & 63) == 0) { rs[w] = s; rs2[w] = s2; }
  __syncthreads();
  const float ts  = rs[0] + rs[1] + rs[2] + rs[3];
  const float ts2 = rs2[0] + rs2[1] + rs2[2] + rs2[3];
  const float mu = ts * (1.f / (float)NNODES);
  const float var = ts2 * (1.f / (float)NNODES) - mu * mu;
  const float rstd = 1.f / sqrtf(var + 1e-5f);
  for (int n = threadIdx.x; n < NNODES; n += 256) {
    float v = scat[(long)n * dout + c] + xw[(long)n * dout + c] * dinv[n] * dinv[n] + bc;
    v = v >= 0.f ? v : 0.01f * v;
    out[(long)n * dout + c] = (v - mu) * rstd;
  }
}

__global__ __launch_bounds__(64) void pool_kernel(
    const float* __restrict__ x, float* __restrict__ emb, float* __restrict__ dout) {
  const int g = blockIdx.x, c = threadIdx.x;
  if (c >= 50) return;
  float s = 0.f;
  for (int r = 0; r < 128; r++) s += x[(long)(g * 128 + r) * 50 + c];
  emb[g * 50 + c] = s;
  dout[16 + g * 50 + c] = s;
}

__global__ __launch_bounds__(64) void fc_head(
    const float* __restrict__ emb,
    const float* __restrict__ w1, const float* __restrict__ b1,
    const float* __restrict__ w2, const float* __restrict__ b2,
    const float* __restrict__ w3, const float* __restrict__ b3,
    float* __restrict__ dout) {
  const int g = threadIdx.x;
  if (g >= NGRAPH) return;
  float e[50];
#pragma unroll
  for (int k = 0; k < 50; k++) e[k] = emb[g * 50 + k];
  float t1[32];
  for (int j = 0; j < 32; j++) {
    float a = b1[j];
    for (int k = 0; k < 50; k++) a = fmaf(e[k], w1[k * 32 + j], a);
    t1[j] = a;
  }
  float t2[16];
  for (int j = 0; j < 16; j++) {
    float a = b2[j];
    for (int k = 0; k < 32; k++) a = fmaf(t1[k], w2[k * 16 + j], a);
    t2[j] = a;
  }
  float y = b3[0];
  for (int k = 0; k < 16; k++) y = fmaf(t2[k], w3[k], y);
  dout[g] = y;
}

// ---------------------------------------------------------------------------
extern "C" void kernel_launch(void* const* d_in, const int* in_sizes, int n_in,
                              void* d_out, int out_size, void* d_ws, size_t ws_size,
                              hipStream_t stream) {
  const float* x_in  = (const float*)d_in[0];
  const int*   eidx  = (const int*)d_in[1];
  const float* w_ih[3] = {(const float*)d_in[2], (const float*)d_in[6],  (const float*)d_in[10]};
  const float* w_hh[3] = {(const float*)d_in[3], (const float*)d_in[7],  (const float*)d_in[11]};
  const float* b_ih[3] = {(const float*)d_in[4], (const float*)d_in[8],  (const float*)d_in[12]};
  const float* b_hh[3] = {(const float*)d_in[5], (const float*)d_in[9],  (const float*)d_in[13]};
  const float* gw[4] = {(const float*)d_in[14], (const float*)d_in[16], (const float*)d_in[18], (const float*)d_in[20]};
  const float* gbv[4] = {(const float*)d_in[15], (const float*)d_in[17], (const float*)d_in[19], (const float*)d_in[21]};
  const float* fw1 = (const float*)d_in[22]; const float* fb1 = (const float*)d_in[23];
  const float* fw2 = (const float*)d_in[24]; const float* fb2 = (const float*)d_in[25];
  const float* fw3 = (const float*)d_in[26]; const float* fb3 = (const float*)d_in[27];
  const int* src = eidx;
  const int* dst = eidx + NEDGE;

  // workspace layout (floats)
  float* ws  = (float*)d_ws;
  float* xp  = ws;                                   // 5,242,880 f
  u64* rec0 = (u64*)(ws + 5242880);                  // 491,520 u64 per layer
  u64* rec1 = rec0 + RECL;
  u64* rec2 = rec1 + RECL;
  float* hs2 = ws + 5242880 + 2949120;               // 1,310,720 f
  unsigned int* deg = (unsigned int*)(hs2 + 1310720);
  float* dinv = (float*)(deg + 2048);
  float* emb  = dinv + 2048;
  // GCN buffers alias the (then-dead) xp region
  float* ga = xp;
  float* gb = xp + 655360;
  float* x0 = xp + 1310720;
  float* x1 = xp + 1966080;

  // seq=0 in all records (expected seqs are >=1); zero deg
  hipMemsetAsync(rec0, 0, (size_t)3 * RECL * sizeof(u64), stream);
  hipMemsetAsync(deg, 0, 2048 * sizeof(unsigned int), stream);

  gemm_mfma<<<dim3(GD / 128, NNODES / 128), 256, 0, stream>>>(
      x_in, w_ih[0], b_ih[0], b_hh[0], xp, NNODES, GD, KIN);

  deg_kernel<<<NEDGE / 256, 256, 0, stream>>>(dst, deg);
  dinv_kernel<<<NNODES / 256, 256, 0, stream>>>(deg, dinv);

  fused_scan<<<3 * LSB, 512, 0, stream>>>(
      xp, w_hh[0], w_ih[1], w_hh[1], b_ih[1], b_hh[1],
      w_ih[2], w_hh[2], b_ih[2], b_hh[2], rec0, rec1, rec2, hs2);

  const int dims_in[4]  = {640, 320, 180, 90};
  const int dims_out[4] = {320, 180, 90, 50};
  const float* xin_l[4] = {hs2, x0, x1, x0};
  float* xout_l[4]      = {x0, x1, x0, x1};
  for (int l = 0; l < 4; l++) {
    gcn_gemm<<<NNODES, 256, 0, stream>>>(xin_l[l], gw[l], ga, dims_in[l], dims_out[l]);
    hipMemsetAsync(gb, 0, (size_t)NNODES * dims_out[l] * sizeof(float), stream);
    gcn_scatter<<<NEDGE, 128, 0, stream>>>(ga, src, dst, dinv, gb, dims_out[l]);
    gcn_bn<<<dims_out[l], 256, 0, stream>>>(gb, ga, dinv, gbv[l], xout_l[l], dims_out[l]);
  }

  pool_kernel<<<NGRAPH, 64, 0, stream>>>(x1, emb, (float*)d_out);
  fc_head<<<1, 64, 0, stream>>>(emb, fw1, fb1, fw2, fb2, fw3, fb3, (float*)d_out);
}

// Round 5
// 6177.459 us; speedup vs baseline: 1.0092x; 1.0092x over previous
//
#include <hip/hip_runtime.h>
#include <stdint.h>

#define NNODES 2048
#define T_SEQ  2048
#define HD     640
#define GD     2560   // 4*HD
#define KIN    8500
#define NEDGE  65536
#define NGRAPH 16

// fused_scan geometry: 3 layers x 80 blocks x 8 dims, 512 threads (8 waves).
// Record row: 80 records x 3 u64 (3 f16 h + 16-bit seq each) = 240 u64.
#define LSB    80     // blocks per layer
#define LDIM   8      // h-dims per block
#define ROW64  240    // u64 per timestep row
#define RECL   (T_SEQ * ROW64)   // u64 per layer record buffer

typedef unsigned long long u64;
typedef _Float16 half2v __attribute__((ext_vector_type(2)));
using short8 = __attribute__((ext_vector_type(8))) short;
using f32x4  = __attribute__((ext_vector_type(4))) float;

#if __has_builtin(__builtin_amdgcn_fdot2)
#define HAVE_FDOT2 1
#endif

__device__ __forceinline__ float dot2acc(unsigned w, unsigned h, float acc) {
#ifdef HAVE_FDOT2
  return __builtin_amdgcn_fdot2(__builtin_bit_cast(half2v, w),
                                __builtin_bit_cast(half2v, h), acc, false);
#else
  acc += (float)__builtin_bit_cast(_Float16, (unsigned short)(w & 0xffffu)) *
         (float)__builtin_bit_cast(_Float16, (unsigned short)(h & 0xffffu));
  acc += (float)__builtin_bit_cast(_Float16, (unsigned short)(w >> 16)) *
         (float)__builtin_bit_cast(_Float16, (unsigned short)(h >> 16));
  return acc;
#endif
}

__device__ __forceinline__ unsigned short f2h(float x) {
  return __builtin_bit_cast(unsigned short, (_Float16)x);
}
__device__ __forceinline__ unsigned packh(float a, float b) {
  return (unsigned)f2h(a) | ((unsigned)f2h(b) << 16);
}
__device__ __forceinline__ unsigned f2bf(float x) {
  unsigned u = __float_as_uint(x);
  return (u + 0x7fffu + ((u >> 16) & 1u)) >> 16;
}
__device__ __forceinline__ unsigned packbf(float a, float b) {
  return f2bf(a) | (f2bf(b) << 16);
}

// ---------------------------------------------------------------------------
// C[M,N] = A[M,K] @ W[N,K]^T + b1[n] + b2[n], bf16 MFMA 16x16x32. (unchanged)
// ---------------------------------------------------------------------------
#define GK 32
__global__ __launch_bounds__(256) void gemm_mfma(
    const float* __restrict__ A, const float* __restrict__ W,
    const float* __restrict__ b1, const float* __restrict__ b2,
    float* __restrict__ C, int M, int N, int K) {
  __shared__ __align__(16) short As[128 * 40];
  __shared__ __align__(16) short Ws[128 * 40];
  const int tid = threadIdx.x;
  const int wave = tid >> 6, lane = tid & 63;
  const int bm = blockIdx.y * 128, bn = blockIdx.x * 128;
  const int wm = (wave >> 1) * 64, wn = (wave & 1) * 64;
  const int mrow = lane & 15, quad = lane >> 4;
  const int srow = tid >> 1, skc = (tid & 1) * 16;
  f32x4 acc[4][4] = {};
  for (int k0 = 0; k0 < K; k0 += GK) {
    float av[16], wv[16];
    if (k0 + GK <= K) {
      const float* Ap = A + (long)(bm + srow) * K + k0 + skc;
      const float* Wp = W + (long)(bn + srow) * K + k0 + skc;
#pragma unroll
      for (int i = 0; i < 4; i++) {
        float4 a4 = *(const float4*)(Ap + 4 * i);
        float4 w4 = *(const float4*)(Wp + 4 * i);
        av[4*i]=a4.x; av[4*i+1]=a4.y; av[4*i+2]=a4.z; av[4*i+3]=a4.w;
        wv[4*i]=w4.x; wv[4*i+1]=w4.y; wv[4*i+2]=w4.z; wv[4*i+3]=w4.w;
      }
    } else {
#pragma unroll
      for (int i = 0; i < 16; i++) {
        const int k = k0 + skc + i;
        av[i] = (k < K) ? A[(long)(bm + srow) * K + k] : 0.f;
        wv[i] = (k < K) ? W[(long)(bn + srow) * K + k] : 0.f;
      }
    }
    __syncthreads();
    {
      uint4* pa = (uint4*)&As[srow * 40 + skc];
      uint4* pw = (uint4*)&Ws[srow * 40 + skc];
      pa[0] = make_uint4(packbf(av[0],av[1]), packbf(av[2],av[3]),
                         packbf(av[4],av[5]), packbf(av[6],av[7]));
      pa[1] = make_uint4(packbf(av[8],av[9]), packbf(av[10],av[11]),
                         packbf(av[12],av[13]), packbf(av[14],av[15]));
      pw[0] = make_uint4(packbf(wv[0],wv[1]), packbf(wv[2],wv[3]),
                         packbf(wv[4],wv[5]), packbf(wv[6],wv[7]));
      pw[1] = make_uint4(packbf(wv[8],wv[9]), packbf(wv[10],wv[11]),
                         packbf(wv[12],wv[13]), packbf(wv[14],wv[15]));
    }
    __syncthreads();
    short8 af[4], bf[4];
#pragma unroll
    for (int mi = 0; mi < 4; mi++)
      af[mi] = *(const short8*)&As[(wm + mi * 16 + mrow) * 40 + quad * 8];
#pragma unroll
    for (int ni = 0; ni < 4; ni++)
      bf[ni] = *(const short8*)&Ws[(wn + ni * 16 + mrow) * 40 + quad * 8];
#pragma unroll
    for (int mi = 0; mi < 4; mi++)
#pragma unroll
      for (int ni = 0; ni < 4; ni++)
        acc[mi][ni] = __builtin_amdgcn_mfma_f32_16x16x32_bf16(
            af[mi], bf[ni], acc[mi][ni], 0, 0, 0);
  }
#pragma unroll
  for (int ni = 0; ni < 4; ni++) {
    const int c = bn + wn + ni * 16 + mrow;
    const float bias = b1[c] + b2[c];
#pragma unroll
    for (int mi = 0; mi < 4; mi++) {
      const int r0 = bm + wm + mi * 16 + quad * 4;
#pragma unroll
      for (int reg = 0; reg < 4; reg++)
        C[(long)(r0 + reg) * N + c] = acc[mi][ni][reg] + bias;
    }
  }
}

// ---------------------------------------------------------------------------
// Fused 3-layer pipelined LSTM scan.
// 80 blocks/layer x 8 dims, 512 threads (8 waves).
// r1-r4 lesson: the allocator will NOT keep a 20-40 u32 loop-invariant weight
// array in VGPRs across the scan loop (remat in r3, spill-despite-pin in r4;
// 225MB/step re-stream either way). So weights live in LDS, stored in exact
// per-lane consumption order: uint4 slot (wv*5+c)*64 + lane, making each
// per-step weight read a linear wave-wide ds_read_b128 (conflict-free,
// ~0.13/0.27us per step, no latency spikes, nothing for the compiler to undo).
// LDS: whh 40KB + wih 40KB + bufs ~4.5KB = 84.5KB -> 1 block/CU (as before).
// Records: 3 u64 per block row (3 f16 h + seq<<48), agent-scope everywhere.
// One __syncthreads per step; pdot parity-double-buffered.
// ---------------------------------------------------------------------------
__global__ __launch_bounds__(512) void fused_scan(
    const float* __restrict__ xp,
    const float* __restrict__ whh0,
    const float* __restrict__ wih1, const float* __restrict__ whh1,
    const float* __restrict__ bih1, const float* __restrict__ bhh1,
    const float* __restrict__ wih2, const float* __restrict__ whh2,
    const float* __restrict__ bih2, const float* __restrict__ bhh2,
    u64* __restrict__ rec0, u64* __restrict__ rec1, u64* __restrict__ rec2,
    float* __restrict__ hs2) {
  const int l = blockIdx.x / LSB, blk = blockIdx.x % LSB;
  const int tid = threadIdx.x, wv = tid >> 6, lane = tid & 63;

  __shared__ uint4 whh_v[2560];                        // 40 KB
  __shared__ uint4 wih_v[2560];                        // 40 KB (l>0 only)
  __shared__ __align__(16) unsigned short hbufh[640];  // own-layer h (t-1)
  __shared__ __align__(16) unsigned short xbufh[640];  // upstream x (t)
  __shared__ float pdot[2][8][32];                     // [parity][wave][row]

  const float* Wih = (l == 1) ? wih1 : wih2;
  const float* Whh = (l == 0) ? whh0 : ((l == 1) ? whh1 : whh2);
  const float* bi  = (l == 1) ? bih1 : bih2;
  const float* bh  = (l == 1) ? bhh1 : bhh2;
  u64* recL = (l == 0) ? rec0 : ((l == 1) ? rec1 : rec2);
  const u64* recU = (l == 1) ? rec0 : rec1;

  // ---- stage weights into LDS in per-lane consumption order (one-time).
  // entry e: wvc=e>>6 (wv2=wvc/5, c2=wvc%5), lane2=e&63 (r=lane2&31,
  // kh=lane2>>5). Holds W[row(r)][k0..k0+8) packed as 4 u32 f16-pairs,
  // k0 = wv2*80 + kh*40 + c2*8, row = (r>>3)*HD + blk*8 + (r&7).
  const int nst = (l > 0) ? 5120 : 2560;
  for (int idx = tid; idx < nst; idx += 512) {
    const int e = (idx >= 2560) ? idx - 2560 : idx;
    const float* Wsrc = (idx >= 2560) ? Wih : Whh;
    uint4* dstv = (idx >= 2560) ? wih_v : whh_v;
    const int wvc = e >> 6, lane2 = e & 63;
    const int wv2 = wvc / 5, c2 = wvc - 5 * wv2;
    const int r2 = lane2 & 31, kh2 = lane2 >> 5;
    const int k0 = wv2 * 80 + kh2 * 40 + c2 * 8;
    const long row = (long)((r2 >> 3) * HD + blk * LDIM + (r2 & 7));
    const float* sp = Wsrc + row * HD + k0;
    const float4 a = *(const float4*)sp;
    const float4 b = *(const float4*)(sp + 4);
    dstv[e] = make_uint4(packh(a.x, a.y), packh(a.z, a.w),
                         packh(b.x, b.y), packh(b.z, b.w));
  }

  // ---- gate-row external term (wave 0, lanes<32): xp row (l==0) or bias sum
  const int gidx = (lane >> 3) * HD + blk * LDIM + (lane & 7);
  float extb = 0.f, creg = 0.f;
  if (wv == 0 && lane < 32)
    extb = (l == 0) ? xp[gidx] : (bi[gidx] + bh[gidx]);

  // ---- zero own h slice (wave-private: dims [80*wv, 80*wv+80))
  unsigned* hbuf32 = (unsigned*)hbufh;
  unsigned* xbuf32 = (unsigned*)xbufh;
  if (lane < 40) { hbuf32[40 * wv + lane] = 0; xbuf32[40 * wv + lane] = 0; }
  __syncthreads();

  // ---- poll geometry: wave covers records [30*wv, 30*wv+30), 3 u64/block.
  // lanes 0..29 poll own layer (t-1); lanes 32..61 poll upstream (t), l>0.
  const int kh = lane >> 5;
  const bool isA = (lane < 30);
  const bool isB = (l > 0) && (lane >= 32) && (lane < 62);
  const int p = isA ? lane : (lane - 32);
  const int dimb = 80 * wv + (p / 3) * LDIM + 3 * (p % 3);
  const int ncnt = ((p % 3) == 2) ? 2 : 3;
  unsigned short* slot = (isA ? hbufh : xbufh) + dimb;

  // per-step weight read pointers (linear wave-wide b128, conflict-free)
  const uint4* whp = whh_v + wv * 320 + lane;
  const uint4* wip = wih_v + wv * 320 + lane;
  const uint4* hb  = (const uint4*)&hbuf32[40 * wv + 20 * kh];
  const uint4* xb  = (const uint4*)&xbuf32[40 * wv + 20 * kh];

  long totspins = 0;
  for (int t = 0; t < T_SEQ; ++t) {
    // ---- poll + unpack
    const bool want = (isA && t > 0) || isB;
    if (want && totspins < 30000000L) {
      const u64* src = isA ? (recL + (long)(t - 1) * ROW64 + 30 * wv + p)
                           : (recU + (long)t * ROW64 + 30 * wv + p);
      const unsigned exps = isA ? (unsigned)t : (unsigned)(t + 1);
      int ss = 0;
      for (;;) {
        const u64 v = __hip_atomic_load(src, __ATOMIC_RELAXED,
                                        __HIP_MEMORY_SCOPE_AGENT);
        if ((unsigned)(v >> 48) == exps) {
          slot[0] = (unsigned short)v;
          slot[1] = (unsigned short)(v >> 16);
          if (ncnt == 3) slot[2] = (unsigned short)(v >> 32);
          break;
        }
        ++totspins;
        if (++ss > 2) __builtin_amdgcn_s_sleep(1);
        if (totspins > 30000000L) break;   // safety: wrong > hung
      }
    }
    __threadfence_block();   // order LDS unpack writes before same-wave reads

    // ---- dot: lane row r=lane&31, k chunk [80*wv + 40*kh, +40).
    // Weights from LDS (b128, linear per wave); h/x broadcast reads.
    float a = 0.f;
    {
      const uint4 w0 = whp[0], w1 = whp[64], w2 = whp[128], w3 = whp[192],
                  w4 = whp[256];
      const uint4 h0 = hb[0], h1 = hb[1], h2 = hb[2], h3 = hb[3], h4 = hb[4];
      a = dot2acc(w0.x, h0.x, a); a = dot2acc(w0.y, h0.y, a);
      a = dot2acc(w0.z, h0.z, a); a = dot2acc(w0.w, h0.w, a);
      a = dot2acc(w1.x, h1.x, a); a = dot2acc(w1.y, h1.y, a);
      a = dot2acc(w1.z, h1.z, a); a = dot2acc(w1.w, h1.w, a);
      a = dot2acc(w2.x, h2.x, a); a = dot2acc(w2.y, h2.y, a);
      a = dot2acc(w2.z, h2.z, a); a = dot2acc(w2.w, h2.w, a);
      a = dot2acc(w3.x, h3.x, a); a = dot2acc(w3.y, h3.y, a);
      a = dot2acc(w3.z, h3.z, a); a = dot2acc(w3.w, h3.w, a);
      a = dot2acc(w4.x, h4.x, a); a = dot2acc(w4.y, h4.y, a);
      a = dot2acc(w4.z, h4.z, a); a = dot2acc(w4.w, h4.w, a);
    }
    if (l > 0) {
      const uint4 w0 = wip[0], w1 = wip[64], w2 = wip[128], w3 = wip[192],
                  w4 = wip[256];
      const uint4 x0 = xb[0], x1 = xb[1], x2 = xb[2], x3 = xb[3], x4 = xb[4];
      a = dot2acc(w0.x, x0.x, a); a = dot2acc(w0.y, x0.y, a);
      a = dot2acc(w0.z, x0.z, a); a = dot2acc(w0.w, x0.w, a);
      a = dot2acc(w1.x, x1.x, a); a = dot2acc(w1.y, x1.y, a);
      a = dot2acc(w1.z, x1.z, a); a = dot2acc(w1.w, x1.w, a);
      a = dot2acc(w2.x, x2.x, a); a = dot2acc(w2.y, x2.y, a);
      a = dot2acc(w2.z, x2.z, a); a = dot2acc(w2.w, x2.w, a);
      a = dot2acc(w3.x, x3.x, a); a = dot2acc(w3.y, x3.y, a);
      a = dot2acc(w3.z, x3.z, a); a = dot2acc(w3.w, x3.w, a);
      a = dot2acc(w4.x, x4.x, a); a = dot2acc(w4.y, x4.y, a);
      a = dot2acc(w4.z, x4.z, a); a = dot2acc(w4.w, x4.w, a);
    }
    a += __shfl_xor(a, 32);                 // combine k-halves
    if (lane < 32) pdot[t & 1][wv][lane] = a;
    __syncthreads();   // pdot ready (single barrier per step)

    // ---- gates (wave 0, lanes<32 rows; lanes<8 cell/output)
    if (wv == 0) {
      const int par = t & 1;
      float av = 0.f;
      if (lane < 32) {
        float s = extb;
#pragma unroll
        for (int w = 0; w < 8; ++w) s += pdot[par][w][lane];
        if ((lane >> 3) == 2) {            // g gate: tanh
          const float e2 = __expf(2.f * s);
          av = 1.f - 2.f / (e2 + 1.f);
        } else {                           // i, f, o: sigmoid
          av = 1.f / (1.f + __expf(-s));
        }
      }
      const float ai = av;
      const float af = __shfl(av, lane + 8);
      const float ag = __shfl(av, lane + 16);
      const float ao = __shfl(av, lane + 24);
      float h = 0.f;
      if (lane < LDIM) {
        creg = af * creg + ai * ag;
        const float e2 = __expf(2.f * creg);
        h = ao * (1.f - 2.f / (e2 + 1.f));
        if (l == 2) hs2[(long)t * HD + blk * LDIM + lane] = h;
      }
      // pack 8 h into 3 u64 (3 f16 + seq each) and publish
      const float ha = __shfl(h, 3 * lane);
      const float hb2 = __shfl(h, 3 * lane + 1);
      const float hc2 = __shfl(h, 3 * lane + 2);
      if (lane < 3) {
        const unsigned seq = (unsigned)(t + 1);
        const u64 val = (u64)((unsigned)f2h(ha) | ((unsigned)f2h(hb2) << 16)) |
                        ((u64)((unsigned)f2h(hc2) | (seq << 16)) << 32);
        __hip_atomic_store(recL + (long)t * ROW64 + 3 * blk + lane, val,
                           __ATOMIC_RELAXED, __HIP_MEMORY_SCOPE_AGENT);
      }
      if (l == 0 && lane < 32 && t + 1 < T_SEQ)
        extb = xp[(long)(t + 1) * GD + gidx];   // prefetch next step
    }
  }
}

// ---------------------------------------------------------------------------
// GCN pieces (unchanged)
// ---------------------------------------------------------------------------
__global__ __launch_bounds__(256) void gcn_gemm(
    const float* __restrict__ X, const float* __restrict__ W,
    float* __restrict__ Y, int di, int dout) {
  __shared__ float xr[640];
  const int n = blockIdx.x;
  for (int k = threadIdx.x; k < di; k += 256) xr[k] = X[(long)n * di + k];
  __syncthreads();
  for (int c = threadIdx.x; c < dout; c += 256) {
    float acc = 0.f;
    for (int k = 0; k < di; k++) acc = fmaf(xr[k], W[(long)k * dout + c], acc);
    Y[(long)n * dout + c] = acc;
  }
}

__global__ void deg_kernel(const int* __restrict__ dst, unsigned int* __restrict__ deg) {
  const int e = blockIdx.x * 256 + threadIdx.x;
  if (e < NEDGE) atomicAdd(&deg[dst[e]], 1u);
}

__global__ void dinv_kernel(const unsigned int* __restrict__ deg, float* __restrict__ dinv) {
  const int n = blockIdx.x * 256 + threadIdx.x;
  if (n < NNODES) dinv[n] = 1.f / sqrtf((float)(deg[n] + 1u));
}

__global__ __launch_bounds__(128) void gcn_scatter(
    const float* __restrict__ XW, const int* __restrict__ src,
    const int* __restrict__ dst, const float* __restrict__ dinv,
    float* __restrict__ out, int dout) {
  const int e = blockIdx.x;
  const int s = src[e], d = dst[e];
  const float nrm = dinv[s] * dinv[d];
  for (int c = threadIdx.x; c < dout; c += 128)
    atomicAdd(&out[(long)d * dout + c], XW[(long)s * dout + c] * nrm);
}

__global__ __launch_bounds__(256) void gcn_bn(
    const float* __restrict__ scat, const float* __restrict__ xw,
    const float* __restrict__ dinv, const float* __restrict__ bias,
    float* __restrict__ out, int dout) {
  const int c = blockIdx.x;
  const float bc = bias[c];
  float s = 0.f, s2 = 0.f;
  for (int n = threadIdx.x; n < NNODES; n += 256) {
    float v = scat[(long)n * dout + c] + xw[(long)n * dout + c] * dinv[n] * dinv[n] + bc;
    v = v >= 0.f ? v : 0.01f * v;
    s += v; s2 += v * v;
  }
  __shared__ float rs[4], rs2[4];
#pragma unroll
  for (int off = 32; off; off >>= 1) { s += __shfl_down(s, off, 64); s2 += __shfl_down(s2, off, 64); }
  const int w = threadIdx.x >> 6;
  if ((threadIdx.x & 63) == 0) { rs[w] = s; rs2[w] = s2; }
  __syncthreads();
  const float ts  = rs[0] + rs[1] + rs[2] + rs[3];
  const float ts2 = rs2[0] + rs2[1] + rs2[2] + rs2[3];
  const float mu = ts * (1.f / (float)NNODES);
  const float var = ts2 * (1.f / (float)NNODES) - mu * mu;
  const float rstd = 1.f / sqrtf(var + 1e-5f);
  for (int n = threadIdx.x; n < NNODES; n += 256) {
    float v = scat[(long)n * dout + c] + xw[(long)n * dout + c] * dinv[n] * dinv[n] + bc;
    v = v >= 0.f ? v : 0.01f * v;
    out[(long)n * dout + c] = (v - mu) * rstd;
  }
}

__global__ __launch_bounds__(64) void pool_kernel(
    const float* __restrict__ x, float* __restrict__ emb, float* __restrict__ dout) {
  const int g = blockIdx.x, c = threadIdx.x;
  if (c >= 50) return;
  float s = 0.f;
  for (int r = 0; r < 128; r++) s += x[(long)(g * 128 + r) * 50 + c];
  emb[g * 50 + c] = s;
  dout[16 + g * 50 + c] = s;
}

__global__ __launch_bounds__(64) void fc_head(
    const float* __restrict__ emb,
    const float* __restrict__ w1, const float* __restrict__ b1,
    const float* __restrict__ w2, const float* __restrict__ b2,
    const float* __restrict__ w3, const float* __restrict__ b3,
    float* __restrict__ dout) {
  const int g = threadIdx.x;
  if (g >= NGRAPH) return;
  float e[50];
#pragma unroll
  for (int k = 0; k < 50; k++) e[k] = emb[g * 50 + k];
  float t1[32];
  for (int j = 0; j < 32; j++) {
    float a = b1[j];
    for (int k = 0; k < 50; k++) a = fmaf(e[k], w1[k * 32 + j], a);
    t1[j] = a;
  }
  float t2[16];
  for (int j = 0; j < 16; j++) {
    float a = b2[j];
    for (int k = 0; k < 32; k++) a = fmaf(t1[k], w2[k * 16 + j], a);
    t2[j] = a;
  }
  float y = b3[0];
  for (int k = 0; k < 16; k++) y = fmaf(t2[k], w3[k], y);
  dout[g] = y;
}

// ---------------------------------------------------------------------------
extern "C" void kernel_launch(void* const* d_in, const int* in_sizes, int n_in,
                              void* d_out, int out_size, void* d_ws, size_t ws_size,
                              hipStream_t stream) {
  const float* x_in  = (const float*)d_in[0];
  const int*   eidx  = (const int*)d_in[1];
  const float* w_ih[3] = {(const float*)d_in[2], (const float*)d_in[6],  (const float*)d_in[10]};
  const float* w_hh[3] = {(const float*)d_in[3], (const float*)d_in[7],  (const float*)d_in[11]};
  const float* b_ih[3] = {(const float*)d_in[4], (const float*)d_in[8],  (const float*)d_in[12]};
  const float* b_hh[3] = {(const float*)d_in[5], (const float*)d_in[9],  (const float*)d_in[13]};
  const float* gw[4] = {(const float*)d_in[14], (const float*)d_in[16], (const float*)d_in[18], (const float*)d_in[20]};
  const float* gbv[4] = {(const float*)d_in[15], (const float*)d_in[17], (const float*)d_in[19], (const float*)d_in[21]};
  const float* fw1 = (const float*)d_in[22]; const float* fb1 = (const float*)d_in[23];
  const float* fw2 = (const float*)d_in[24]; const float* fb2 = (const float*)d_in[25];
  const float* fw3 = (const float*)d_in[26]; const float* fb3 = (const float*)d_in[27];
  const int* src = eidx;
  const int* dst = eidx + NEDGE;

  // workspace layout (floats)
  float* ws  = (float*)d_ws;
  float* xp  = ws;                                   // 5,242,880 f
  u64* rec0 = (u64*)(ws + 5242880);                  // 491,520 u64 per layer
  u64* rec1 = rec0 + RECL;
  u64* rec2 = rec1 + RECL;
  float* hs2 = ws + 5242880 + 2949120;               // 1,310,720 f
  unsigned int* deg = (unsigned int*)(hs2 + 1310720);
  float* dinv = (float*)(deg + 2048);
  float* emb  = dinv + 2048;
  // GCN buffers alias the (then-dead) xp region
  float* ga = xp;
  float* gb = xp + 655360;
  float* x0 = xp + 1310720;
  float* x1 = xp + 1966080;

  // seq=0 in all records (expected seqs are >=1); zero deg
  hipMemsetAsync(rec0, 0, (size_t)3 * RECL * sizeof(u64), stream);
  hipMemsetAsync(deg, 0, 2048 * sizeof(unsigned int), stream);

  gemm_mfma<<<dim3(GD / 128, NNODES / 128), 256, 0, stream>>>(
      x_in, w_ih[0], b_ih[0], b_hh[0], xp, NNODES, GD, KIN);

  deg_kernel<<<NEDGE / 256, 256, 0, stream>>>(dst, deg);
  dinv_kernel<<<NNODES / 256, 256, 0, stream>>>(deg, dinv);

  fused_scan<<<3 * LSB, 512, 0, stream>>>(
      xp, w_hh[0], w_ih[1], w_hh[1], b_ih[1], b_hh[1],
      w_ih[2], w_hh[2], b_ih[2], b_hh[2], rec0, rec1, rec2, hs2);

  const int dims_in[4]  = {640, 320, 180, 90};
  const int dims_out[4] = {320, 180, 90, 50};
  const float* xin_l[4] = {hs2, x0, x1, x0};
  float* xout_l[4]      = {x0, x1, x0, x1};
  for (int l = 0; l < 4; l++) {
    gcn_gemm<<<NNODES, 256, 0, stream>>>(xin_l[l], gw[l], ga, dims_in[l], dims_out[l]);
    hipMemsetAsync(gb, 0, (size_t)NNODES * dims_out[l] * sizeof(float), stream);
    gcn_scatter<<<NEDGE, 128, 0, stream>>>(ga, src, dst, dinv, gb, dims_out[l]);
    gcn_bn<<<dims_out[l], 256, 0, stream>>>(gb, ga, dinv, gbv[l], xout_l[l], dims_out[l]);
  }

  pool_kernel<<<NGRAPH, 64, 0, stream>>>(x1, emb, (float*)d_out);
  fc_head<<<1, 64, 0, stream>>>(emb, fw1, fb1, fw2, fb2, fw3, fb3, (float*)d_out);
}